// Round 12
// baseline (64.038 us; speedup 1.0000x reference)
//
#include <hip/hip_runtime.h>
#include <stdint.h>

#define NB 4096      // B
#define NT 819200    // T
#define NI 100000    // num items
#define MUF 3.5f

// ---- ws layout (bytes) ----
// XYp : uint2[NI*16] -> 128 B/item: lane l holds dims 8l..8l+7; v.x = 8 X-nibbles (LSB=dim 8l), v.y = 8 Y-nibbles
// SC  : float4[NI]   -> {sx = rowmaxX/7, sy = rowmaxY/7, bi[i], 0}
#define XYP_OFF 0u
#define SC_OFF  12800000u
#define WS_NEEDED (12800000u + 1600000u)   // 14,400,000 B

// ============ K0: per-item max-abs scale + int4 quantize ============
__global__ __launch_bounds__(256) void k_quant4(const float* __restrict__ X,
                                                const float* __restrict__ Y,
                                                const float* __restrict__ bi,
                                                char* __restrict__ ws) {
    const int tid = threadIdx.x;
    const int i = blockIdx.x * 16 + (tid >> 4);   // item
    const int l = tid & 15;                       // dims 8l..8l+7
    if (i >= NI) return;
    uint2* XYp = (uint2*)(ws + XYP_OFF);
    float4* SC = (float4*)(ws + SC_OFF);
    const float4* X4 = (const float4*)X;
    const float4* Y4 = (const float4*)Y;

    float4 xa = X4[(size_t)i * 32 + 2 * l];
    float4 xb = X4[(size_t)i * 32 + 2 * l + 1];
    float4 ya = Y4[(size_t)i * 32 + 2 * l];
    float4 yb = Y4[(size_t)i * 32 + 2 * l + 1];

    float mx = fmaxf(fmaxf(fmaxf(fabsf(xa.x), fabsf(xa.y)), fmaxf(fabsf(xa.z), fabsf(xa.w))),
                     fmaxf(fmaxf(fabsf(xb.x), fabsf(xb.y)), fmaxf(fabsf(xb.z), fabsf(xb.w))));
    float my = fmaxf(fmaxf(fmaxf(fabsf(ya.x), fabsf(ya.y)), fmaxf(fabsf(ya.z), fabsf(ya.w))),
                     fmaxf(fmaxf(fabsf(yb.x), fabsf(yb.y)), fmaxf(fabsf(yb.z), fabsf(yb.w))));
    #pragma unroll
    for (int m = 8; m > 0; m >>= 1) {
        mx = fmaxf(mx, __shfl_xor(mx, m, 64));
        my = fmaxf(my, __shfl_xor(my, m, 64));
    }
    const float invx = (mx > 0.f) ? 7.0f / mx : 0.f;
    const float invy = (my > 0.f) ? 7.0f / my : 0.f;

    auto q1 = [](float x, float inv) -> uint32_t {
        float v = fminf(fmaxf(x * inv, -7.0f), 7.0f);
        return (uint32_t)(__float2int_rn(v) & 15);
    };
    uint2 v;
    v.x = q1(xa.x, invx)       | (q1(xa.y, invx) << 4)  | (q1(xa.z, invx) << 8)  | (q1(xa.w, invx) << 12) |
          (q1(xb.x, invx) << 16)| (q1(xb.y, invx) << 20)| (q1(xb.z, invx) << 24) | (q1(xb.w, invx) << 28);
    v.y = q1(ya.x, invy)       | (q1(ya.y, invy) << 4)  | (q1(ya.z, invy) << 8)  | (q1(ya.w, invy) << 12) |
          (q1(yb.x, invy) << 16)| (q1(yb.y, invy) << 20)| (q1(yb.z, invy) << 24) | (q1(yb.w, invy) << 28);
    XYp[(size_t)i * 16 + l] = v;
    if (l == 0) SC[i] = make_float4(mx * (1.0f / 7.0f), my * (1.0f / 7.0f), bi[i], 0.f);
}

// ============ K1: main — 16 groups/block, 16 lanes/row, int4 dot, unroll 8 ============
__global__ __launch_bounds__(256) void asvd_main(
    const float* __restrict__ bu, const float* __restrict__ bi,
    const float* __restrict__ Q,
    const int* __restrict__ user, const int* __restrict__ item,
    const int* __restrict__ imp_items, const int* __restrict__ imp_ratings,
    const int* __restrict__ seg,
    const char* __restrict__ ws, float* __restrict__ out)
{
    const int b   = blockIdx.x;
    const int tid = threadIdx.x;

    auto lower = [&](int key) {
        int lo = 0, hi = NT;
        while (lo < hi) {
            int mid = (lo + hi) >> 1;
            if (seg[mid] < key) lo = mid + 1; else hi = mid;
        }
        return lo;
    };
    const int start = lower(b);
    const int end   = lower(b + 1);
    const int count = end - start;

    const int   it   = item[b];
    const float bu_u = bu[user[b]];
    const float bui  = MUF + bu_u + bi[it];
    const float base = 0.0f - MUF - bu_u;   // w = r + base - bi[j]

    const int g = tid >> 4;   // entry group 0..15
    const int l = tid & 15;   // 8B slot (dims 8l..8l+7)

    const uint2* __restrict__ XYp = (const uint2*)(ws + XYP_OFF);
    const float4* __restrict__ SC = (const float4*)(ws + SC_OFF);

    // ---- quantize this block's q (lane's 8 dims) to int4, per-lane scale ----
    const float4* Q4 = (const float4*)Q;
    const float4 qa = Q4[(size_t)it * 32 + 2 * l];
    const float4 qb = Q4[(size_t)it * 32 + 2 * l + 1];
    float qm = fmaxf(fmaxf(fmaxf(fabsf(qa.x), fabsf(qa.y)), fmaxf(fabsf(qa.z), fabsf(qa.w))),
                     fmaxf(fmaxf(fabsf(qb.x), fabsf(qb.y)), fmaxf(fabsf(qb.z), fabsf(qb.w))));
    const float qinv = (qm > 0.f) ? 7.0f / qm : 0.f;
    const float sq   = qm * (1.0f / 7.0f);
    auto q1 = [&](float x) -> uint32_t {
        float v = fminf(fmaxf(x * qinv, -7.0f), 7.0f);
        return (uint32_t)(__float2int_rn(v) & 15);
    };
    const uint32_t qp = q1(qa.x)        | (q1(qa.y) << 4)  | (q1(qa.z) << 8)  | (q1(qa.w) << 12) |
                        (q1(qb.x) << 16)| (q1(qb.y) << 20) | (q1(qb.z) << 24) | (q1(qb.w) << 28);

#if defined(__HIP_DEVICE_COMPILE__) && defined(__has_builtin)
#if __has_builtin(__builtin_amdgcn_sdot8)
#define DOT8(a, b) __builtin_amdgcn_sdot8((int)(a), (int)(b), 0, false)
#endif
#endif
#ifndef DOT8
    auto dot8_sw = [](uint32_t a, uint32_t b) -> int {
        int s = 0;
        #pragma unroll
        for (int k = 0; k < 8; ++k) {
            int av = ((int)(a << (28 - 4 * k))) >> 28;
            int bv = ((int)(b << (28 - 4 * k))) >> 28;
            s += av * bv;
        }
        return s;
    };
#define DOT8(a, b) dot8_sw((a), (b))
#endif

    float accA = 0.f, accB = 0.f, accC = 0.f, accD = 0.f;

    int t = start + g;
    // unroll 8: 8 independent idx->row chains in flight per group
    for (; t + 112 < end; t += 128) {
        const int j0 = imp_items[t];
        const int j1 = imp_items[t + 16];
        const int j2 = imp_items[t + 32];
        const int j3 = imp_items[t + 48];
        const int j4 = imp_items[t + 64];
        const int j5 = imp_items[t + 80];
        const int j6 = imp_items[t + 96];
        const int j7 = imp_items[t + 112];
        const int r0 = imp_ratings[t];
        const int r1 = imp_ratings[t + 16];
        const int r2 = imp_ratings[t + 32];
        const int r3 = imp_ratings[t + 48];
        const int r4 = imp_ratings[t + 64];
        const int r5 = imp_ratings[t + 80];
        const int r6 = imp_ratings[t + 96];
        const int r7 = imp_ratings[t + 112];
        const float4 s0 = SC[j0];
        const float4 s1 = SC[j1];
        const float4 s2 = SC[j2];
        const float4 s3 = SC[j3];
        const float4 s4 = SC[j4];
        const float4 s5 = SC[j5];
        const float4 s6 = SC[j6];
        const float4 s7 = SC[j7];
        const uint2 v0 = XYp[(size_t)j0 * 16 + l];
        const uint2 v1 = XYp[(size_t)j1 * 16 + l];
        const uint2 v2 = XYp[(size_t)j2 * 16 + l];
        const uint2 v3 = XYp[(size_t)j3 * 16 + l];
        const uint2 v4 = XYp[(size_t)j4 * 16 + l];
        const uint2 v5 = XYp[(size_t)j5 * 16 + l];
        const uint2 v6 = XYp[(size_t)j6 * 16 + l];
        const uint2 v7 = XYp[(size_t)j7 * 16 + l];
        const float w0 = ((float)r0 + base - s0.z) * s0.x;
        const float w1 = ((float)r1 + base - s1.z) * s1.x;
        const float w2 = ((float)r2 + base - s2.z) * s2.x;
        const float w3 = ((float)r3 + base - s3.z) * s3.x;
        const float w4 = ((float)r4 + base - s4.z) * s4.x;
        const float w5 = ((float)r5 + base - s5.z) * s5.x;
        const float w6 = ((float)r6 + base - s6.z) * s6.x;
        const float w7 = ((float)r7 + base - s7.z) * s7.x;
        accA += w0 * (float)DOT8(qp, v0.x);
        accB += s0.y * (float)DOT8(qp, v0.y);
        accC += w1 * (float)DOT8(qp, v1.x);
        accD += s1.y * (float)DOT8(qp, v1.y);
        accA += w2 * (float)DOT8(qp, v2.x);
        accB += s2.y * (float)DOT8(qp, v2.y);
        accC += w3 * (float)DOT8(qp, v3.x);
        accD += s3.y * (float)DOT8(qp, v3.y);
        accA += w4 * (float)DOT8(qp, v4.x);
        accB += s4.y * (float)DOT8(qp, v4.y);
        accC += w5 * (float)DOT8(qp, v5.x);
        accD += s5.y * (float)DOT8(qp, v5.y);
        accA += w6 * (float)DOT8(qp, v6.x);
        accB += s6.y * (float)DOT8(qp, v6.y);
        accC += w7 * (float)DOT8(qp, v7.x);
        accD += s7.y * (float)DOT8(qp, v7.y);
    }
    // unroll-2 tail
    for (; t + 16 < end; t += 32) {
        const int j0 = imp_items[t];
        const int j1 = imp_items[t + 16];
        const int r0 = imp_ratings[t];
        const int r1 = imp_ratings[t + 16];
        const float4 s0 = SC[j0];
        const float4 s1 = SC[j1];
        const uint2 v0 = XYp[(size_t)j0 * 16 + l];
        const uint2 v1 = XYp[(size_t)j1 * 16 + l];
        const float w0 = ((float)r0 + base - s0.z) * s0.x;
        const float w1 = ((float)r1 + base - s1.z) * s1.x;
        accA += w0 * (float)DOT8(qp, v0.x);
        accB += s0.y * (float)DOT8(qp, v0.y);
        accC += w1 * (float)DOT8(qp, v1.x);
        accD += s1.y * (float)DOT8(qp, v1.y);
    }
    for (; t < end; t += 16) {
        const int j = imp_items[t];
        const float4 s = SC[j];
        const uint2 v = XYp[(size_t)j * 16 + l];
        const float w = ((float)imp_ratings[t] + base - s.z) * s.x;
        accA += w * (float)DOT8(qp, v.x);
        accB += s.y * (float)DOT8(qp, v.y);
    }
#undef DOT8

    float partial = sq * (accA + accB + accC + accD);

    #pragma unroll
    for (int m = 8; m > 0; m >>= 1)
        partial += __shfl_xor(partial, m, 64);

    __shared__ float red[16];
    if (l == 0) red[g] = partial;
    __syncthreads();
    if (tid == 0) {
        float tot = 0.f;
        #pragma unroll
        for (int i = 0; i < 16; ++i) tot += red[i];
        const float norm = (count > 0) ? rsqrtf((float)count) : 1.0f;
        out[b] = bui + norm * tot;
    }
}

// ============ fallback (round-1 kernel) ============
__global__ __launch_bounds__(256) void asvd_fallback(
    const float* __restrict__ bu, const float* __restrict__ bi,
    const float* __restrict__ Q,  const float* __restrict__ X,
    const float* __restrict__ Y,
    const int* __restrict__ user, const int* __restrict__ item,
    const int* __restrict__ imp_items, const int* __restrict__ imp_ratings,
    const int* __restrict__ seg, float* __restrict__ out)
{
    const int b   = blockIdx.x;
    const int tid = threadIdx.x;
    auto lower = [&](int key) {
        int lo = 0, hi = NT;
        while (lo < hi) {
            int mid = (lo + hi) >> 1;
            if (seg[mid] < key) lo = mid + 1; else hi = mid;
        }
        return lo;
    };
    const int start = lower(b);
    const int end   = lower(b + 1);
    const int count = end - start;
    const int   u    = user[b];
    const int   it   = item[b];
    const float bu_u = bu[u];
    const float bui  = MUF + bu_u + bi[it];
    const int g = tid >> 5;
    const int l = tid & 31;
    const float4* X4 = (const float4*)X;
    const float4* Y4 = (const float4*)Y;
    const float4* Q4 = (const float4*)Q;
    float4 acc = make_float4(0.f, 0.f, 0.f, 0.f);
    for (int t = start + g; t < end; t += 8) {
        const int   j = imp_items[t];
        const float w = (float)imp_ratings[t] - MUF - bu_u - bi[j];
        const float4 x = X4[(size_t)j * 32 + l];
        const float4 y = Y4[(size_t)j * 32 + l];
        acc.x += w * x.x + y.x;  acc.y += w * x.y + y.y;
        acc.z += w * x.z + y.z;  acc.w += w * x.w + y.w;
    }
    const float4 q = Q4[(size_t)it * 32 + l];
    float partial = acc.x * q.x + acc.y * q.y + acc.z * q.z + acc.w * q.w;
    #pragma unroll
    for (int off = 32; off > 0; off >>= 1)
        partial += __shfl_down(partial, off, 64);
    __shared__ float red[4];
    if ((tid & 63) == 0) red[tid >> 6] = partial;
    __syncthreads();
    if (tid == 0) {
        const float total = red[0] + red[1] + red[2] + red[3];
        const float norm  = (count > 0) ? rsqrtf((float)count) : 1.0f;
        out[b] = bui + norm * total;
    }
}

extern "C" void kernel_launch(void* const* d_in, const int* in_sizes, int n_in,
                              void* d_out, int out_size, void* d_ws, size_t ws_size,
                              hipStream_t stream) {
    const float* bu = (const float*)d_in[0];
    const float* bi = (const float*)d_in[1];
    const float* Q  = (const float*)d_in[2];
    const float* X  = (const float*)d_in[3];
    const float* Y  = (const float*)d_in[4];
    const int* user        = (const int*)d_in[5];
    const int* item        = (const int*)d_in[6];
    const int* imp_items   = (const int*)d_in[7];
    const int* imp_ratings = (const int*)d_in[8];
    const int* seg         = (const int*)d_in[9];
    float* out = (float*)d_out;

    if (ws_size < (size_t)WS_NEEDED) {
        asvd_fallback<<<NB, 256, 0, stream>>>(bu, bi, Q, X, Y, user, item,
                                              imp_items, imp_ratings, seg, out);
        return;
    }
    char* ws = (char*)d_ws;

    k_quant4<<<(NI + 15) / 16, 256, 0, stream>>>(X, Y, bi, ws);
    asvd_main<<<NB, 256, 0, stream>>>(bu, bi, Q, user, item,
                                      imp_items, imp_ratings, seg, ws, out);
}

// Round 13
// 55.609 us; speedup vs baseline: 1.1516x; 1.1516x over previous
//
#include <hip/hip_runtime.h>
#include <stdint.h>

#define NB 4096      // B
#define NT 819200    // T
#define NI 100000    // num items
#define MUF 3.5f

// ---- ws layout (bytes) ----
// XYp : uint2[NI*16] -> 128 B/item: lane l holds dims 8l..8l+7; v.x = 8 X-nibbles (LSB=dim 8l), v.y = 8 Y-nibbles
// SC  : float4[NI]   -> {sx = rowmaxX/7, sy = rowmaxY/7, bi[i], 0}
#define XYP_OFF 0u
#define SC_OFF  12800000u
#define WS_NEEDED (12800000u + 1600000u)   // 14,400,000 B

// ============ K0: per-item max-abs scale + int4 quantize ============
__global__ __launch_bounds__(256) void k_quant4(const float* __restrict__ X,
                                                const float* __restrict__ Y,
                                                const float* __restrict__ bi,
                                                char* __restrict__ ws) {
    const int tid = threadIdx.x;
    const int i = blockIdx.x * 16 + (tid >> 4);   // item
    const int l = tid & 15;                       // dims 8l..8l+7
    if (i >= NI) return;
    uint2* XYp = (uint2*)(ws + XYP_OFF);
    float4* SC = (float4*)(ws + SC_OFF);
    const float4* X4 = (const float4*)X;
    const float4* Y4 = (const float4*)Y;

    float4 xa = X4[(size_t)i * 32 + 2 * l];
    float4 xb = X4[(size_t)i * 32 + 2 * l + 1];
    float4 ya = Y4[(size_t)i * 32 + 2 * l];
    float4 yb = Y4[(size_t)i * 32 + 2 * l + 1];

    float mx = fmaxf(fmaxf(fmaxf(fabsf(xa.x), fabsf(xa.y)), fmaxf(fabsf(xa.z), fabsf(xa.w))),
                     fmaxf(fmaxf(fabsf(xb.x), fabsf(xb.y)), fmaxf(fabsf(xb.z), fabsf(xb.w))));
    float my = fmaxf(fmaxf(fmaxf(fabsf(ya.x), fabsf(ya.y)), fmaxf(fabsf(ya.z), fabsf(ya.w))),
                     fmaxf(fmaxf(fabsf(yb.x), fabsf(yb.y)), fmaxf(fabsf(yb.z), fabsf(yb.w))));
    #pragma unroll
    for (int m = 8; m > 0; m >>= 1) {
        mx = fmaxf(mx, __shfl_xor(mx, m, 64));
        my = fmaxf(my, __shfl_xor(my, m, 64));
    }
    const float invx = (mx > 0.f) ? 7.0f / mx : 0.f;
    const float invy = (my > 0.f) ? 7.0f / my : 0.f;

    auto q1 = [](float x, float inv) -> uint32_t {
        float v = fminf(fmaxf(x * inv, -7.0f), 7.0f);
        return (uint32_t)(__float2int_rn(v) & 15);
    };
    uint2 v;
    v.x = q1(xa.x, invx)       | (q1(xa.y, invx) << 4)  | (q1(xa.z, invx) << 8)  | (q1(xa.w, invx) << 12) |
          (q1(xb.x, invx) << 16)| (q1(xb.y, invx) << 20)| (q1(xb.z, invx) << 24) | (q1(xb.w, invx) << 28);
    v.y = q1(ya.x, invy)       | (q1(ya.y, invy) << 4)  | (q1(ya.z, invy) << 8)  | (q1(ya.w, invy) << 12) |
          (q1(yb.x, invy) << 16)| (q1(yb.y, invy) << 20)| (q1(yb.z, invy) << 24) | (q1(yb.w, invy) << 28);
    XYp[(size_t)i * 16 + l] = v;
    if (l == 0) SC[i] = make_float4(mx * (1.0f / 7.0f), my * (1.0f / 7.0f), bi[i], 0.f);
}

// ============ K1: main — 16 groups/block, 16 lanes/row, int4 dot ============
__global__ __launch_bounds__(256) void asvd_main(
    const float* __restrict__ bu, const float* __restrict__ bi,
    const float* __restrict__ Q,
    const int* __restrict__ user, const int* __restrict__ item,
    const int* __restrict__ imp_items, const int* __restrict__ imp_ratings,
    const int* __restrict__ seg,
    const char* __restrict__ ws, float* __restrict__ out)
{
    const int b   = blockIdx.x;
    const int tid = threadIdx.x;

    auto lower = [&](int key) {
        int lo = 0, hi = NT;
        while (lo < hi) {
            int mid = (lo + hi) >> 1;
            if (seg[mid] < key) lo = mid + 1; else hi = mid;
        }
        return lo;
    };
    const int start = lower(b);
    const int end   = lower(b + 1);
    const int count = end - start;

    const int   it   = item[b];
    const float bu_u = bu[user[b]];
    const float bui  = MUF + bu_u + bi[it];
    const float base = 0.0f - MUF - bu_u;   // w = r + base - bi[j]

    const int g = tid >> 4;   // entry group 0..15
    const int l = tid & 15;   // 8B slot (dims 8l..8l+7)

    const uint2* __restrict__ XYp = (const uint2*)(ws + XYP_OFF);
    const float4* __restrict__ SC = (const float4*)(ws + SC_OFF);

    // ---- quantize this block's q (lane's 8 dims) to int4, per-lane scale ----
    const float4* Q4 = (const float4*)Q;
    const float4 qa = Q4[(size_t)it * 32 + 2 * l];
    const float4 qb = Q4[(size_t)it * 32 + 2 * l + 1];
    float qm = fmaxf(fmaxf(fmaxf(fabsf(qa.x), fabsf(qa.y)), fmaxf(fabsf(qa.z), fabsf(qa.w))),
                     fmaxf(fmaxf(fabsf(qb.x), fabsf(qb.y)), fmaxf(fabsf(qb.z), fabsf(qb.w))));
    const float qinv = (qm > 0.f) ? 7.0f / qm : 0.f;
    const float sq   = qm * (1.0f / 7.0f);
    auto q1 = [&](float x) -> uint32_t {
        float v = fminf(fmaxf(x * qinv, -7.0f), 7.0f);
        return (uint32_t)(__float2int_rn(v) & 15);
    };
    const uint32_t qp = q1(qa.x)        | (q1(qa.y) << 4)  | (q1(qa.z) << 8)  | (q1(qa.w) << 12) |
                        (q1(qb.x) << 16)| (q1(qb.y) << 20) | (q1(qb.z) << 24) | (q1(qb.w) << 28);

#if defined(__HIP_DEVICE_COMPILE__) && defined(__has_builtin)
#if __has_builtin(__builtin_amdgcn_sdot8)
#define DOT8(a, b) __builtin_amdgcn_sdot8((int)(a), (int)(b), 0, false)
#endif
#endif
#ifndef DOT8
    auto dot8_sw = [](uint32_t a, uint32_t b) -> int {
        int s = 0;
        #pragma unroll
        for (int k = 0; k < 8; ++k) {
            int av = ((int)(a << (28 - 4 * k))) >> 28;
            int bv = ((int)(b << (28 - 4 * k))) >> 28;
            s += av * bv;
        }
        return s;
    };
#define DOT8(a, b) dot8_sw((a), (b))
#endif

    float accX0 = 0.f, accY0 = 0.f, accX1 = 0.f, accY1 = 0.f;

    int t = start + g;
    for (; t + 48 < end; t += 64) {
        const int j0 = imp_items[t];
        const int j1 = imp_items[t + 16];
        const int j2 = imp_items[t + 32];
        const int j3 = imp_items[t + 48];
        const int r0 = imp_ratings[t];
        const int r1 = imp_ratings[t + 16];
        const int r2 = imp_ratings[t + 32];
        const int r3 = imp_ratings[t + 48];
        const float4 s0 = SC[j0];
        const float4 s1 = SC[j1];
        const float4 s2 = SC[j2];
        const float4 s3 = SC[j3];
        const uint2 v0 = XYp[(size_t)j0 * 16 + l];
        const uint2 v1 = XYp[(size_t)j1 * 16 + l];
        const uint2 v2 = XYp[(size_t)j2 * 16 + l];
        const uint2 v3 = XYp[(size_t)j3 * 16 + l];
        const float w0 = ((float)r0 + base - s0.z) * s0.x;
        const float w1 = ((float)r1 + base - s1.z) * s1.x;
        const float w2 = ((float)r2 + base - s2.z) * s2.x;
        const float w3 = ((float)r3 + base - s3.z) * s3.x;
        accX0 += w0 * (float)DOT8(qp, v0.x);
        accY0 += s0.y * (float)DOT8(qp, v0.y);
        accX1 += w1 * (float)DOT8(qp, v1.x);
        accY1 += s1.y * (float)DOT8(qp, v1.y);
        accX0 += w2 * (float)DOT8(qp, v2.x);
        accY0 += s2.y * (float)DOT8(qp, v2.y);
        accX1 += w3 * (float)DOT8(qp, v3.x);
        accY1 += s3.y * (float)DOT8(qp, v3.y);
    }
    for (; t < end; t += 16) {
        const int j = imp_items[t];
        const float4 s = SC[j];
        const uint2 v = XYp[(size_t)j * 16 + l];
        const float w = ((float)imp_ratings[t] + base - s.z) * s.x;
        accX0 += w * (float)DOT8(qp, v.x);
        accY0 += s.y * (float)DOT8(qp, v.y);
    }
#undef DOT8

    float partial = sq * (accX0 + accX1 + accY0 + accY1);

    #pragma unroll
    for (int m = 8; m > 0; m >>= 1)
        partial += __shfl_xor(partial, m, 64);

    __shared__ float red[16];
    if (l == 0) red[g] = partial;
    __syncthreads();
    if (tid == 0) {
        float tot = 0.f;
        #pragma unroll
        for (int i = 0; i < 16; ++i) tot += red[i];
        const float norm = (count > 0) ? rsqrtf((float)count) : 1.0f;
        out[b] = bui + norm * tot;
    }
}

// ============ fallback (round-1 kernel) ============
__global__ __launch_bounds__(256) void asvd_fallback(
    const float* __restrict__ bu, const float* __restrict__ bi,
    const float* __restrict__ Q,  const float* __restrict__ X,
    const float* __restrict__ Y,
    const int* __restrict__ user, const int* __restrict__ item,
    const int* __restrict__ imp_items, const int* __restrict__ imp_ratings,
    const int* __restrict__ seg, float* __restrict__ out)
{
    const int b   = blockIdx.x;
    const int tid = threadIdx.x;
    auto lower = [&](int key) {
        int lo = 0, hi = NT;
        while (lo < hi) {
            int mid = (lo + hi) >> 1;
            if (seg[mid] < key) lo = mid + 1; else hi = mid;
        }
        return lo;
    };
    const int start = lower(b);
    const int end   = lower(b + 1);
    const int count = end - start;
    const int   u    = user[b];
    const int   it   = item[b];
    const float bu_u = bu[u];
    const float bui  = MUF + bu_u + bi[it];
    const int g = tid >> 5;
    const int l = tid & 31;
    const float4* X4 = (const float4*)X;
    const float4* Y4 = (const float4*)Y;
    const float4* Q4 = (const float4*)Q;
    float4 acc = make_float4(0.f, 0.f, 0.f, 0.f);
    for (int t = start + g; t < end; t += 8) {
        const int   j = imp_items[t];
        const float w = (float)imp_ratings[t] - MUF - bu_u - bi[j];
        const float4 x = X4[(size_t)j * 32 + l];
        const float4 y = Y4[(size_t)j * 32 + l];
        acc.x += w * x.x + y.x;  acc.y += w * x.y + y.y;
        acc.z += w * x.z + y.z;  acc.w += w * x.w + y.w;
    }
    const float4 q = Q4[(size_t)it * 32 + l];
    float partial = acc.x * q.x + acc.y * q.y + acc.z * q.z + acc.w * q.w;
    #pragma unroll
    for (int off = 32; off > 0; off >>= 1)
        partial += __shfl_down(partial, off, 64);
    __shared__ float red[4];
    if ((tid & 63) == 0) red[tid >> 6] = partial;
    __syncthreads();
    if (tid == 0) {
        const float total = red[0] + red[1] + red[2] + red[3];
        const float norm  = (count > 0) ? rsqrtf((float)count) : 1.0f;
        out[b] = bui + norm * total;
    }
}

extern "C" void kernel_launch(void* const* d_in, const int* in_sizes, int n_in,
                              void* d_out, int out_size, void* d_ws, size_t ws_size,
                              hipStream_t stream) {
    const float* bu = (const float*)d_in[0];
    const float* bi = (const float*)d_in[1];
    const float* Q  = (const float*)d_in[2];
    const float* X  = (const float*)d_in[3];
    const float* Y  = (const float*)d_in[4];
    const int* user        = (const int*)d_in[5];
    const int* item        = (const int*)d_in[6];
    const int* imp_items   = (const int*)d_in[7];
    const int* imp_ratings = (const int*)d_in[8];
    const int* seg         = (const int*)d_in[9];
    float* out = (float*)d_out;

    if (ws_size < (size_t)WS_NEEDED) {
        asvd_fallback<<<NB, 256, 0, stream>>>(bu, bi, Q, X, Y, user, item,
                                              imp_items, imp_ratings, seg, out);
        return;
    }
    char* ws = (char*)d_ws;

    k_quant4<<<(NI + 15) / 16, 256, 0, stream>>>(X, Y, bi, ws);
    asvd_main<<<NB, 256, 0, stream>>>(bu, bi, Q, user, item,
                                      imp_items, imp_ratings, seg, ws, out);
}